// Round 6
// baseline (154.503 us; speedup 1.0000x reference)
//
#include <hip/hip_runtime.h>

#define NPG 64
#define IN 16
#define DM 128
#define NOUT 64
#define EPG 4096
#define BN_EPS 1e-5f

// ---------------------------------------------------------------------------
// Coherence: cross-phase STORES are agent-scope relaxed atomics (sc1
// write-through -> IC; no dirty L2 lines, no release writeback needed).
// Cross-phase READS are PLAIN vectorized loads, made safe by an
// acquire-only fence (L1/L2 invalidate, no writeback) after each barrier.
// This mimics what kernel-dispatch boundaries do implicitly, cheaply.
// ---------------------------------------------------------------------------
__device__ __forceinline__ void stg(float* p, float v) {
    __hip_atomic_store(p, v, __ATOMIC_RELAXED, __HIP_MEMORY_SCOPE_AGENT);
}

// ---------------------------------------------------------------------------
// Grid barrier (r5-proven mechanics + acquire-inv). ctrl u32 layout
// (memset 0 each launch): epoch e in 1..3: sub[8] @ e*160+sg*16, root @
// e*160+128; flags[256] stride16 @ 1024. Arrival: spread-line RMWs; release:
// root stores 256 private lines; t0-only polls; t0 issues acquire fence
// (per-CU L1 + per-XCD L2 invalidate) before releasing the block.
// Profiler replays without memset see flags>=e and fall through (no hang).
// ---------------------------------------------------------------------------
__device__ __forceinline__ void gbar(unsigned* bu, unsigned e, int bid, int t,
                                     bool wait) {
    __syncthreads();   // drains vmcnt -> all sc1 stores complete at IC
    if (t == 0) {
        unsigned* sub   = bu + e * 160 + (bid & 7) * 16;
        unsigned* root  = bu + e * 160 + 128;
        unsigned* flags = bu + 1024;
        if (atomicAdd(sub, 1u) == 31u)
            if (atomicAdd(root, 1u) == 7u)
                for (int i = 0; i < 256; i++)
                    __hip_atomic_store(&flags[i * 16], e,
                                       __ATOMIC_RELAXED, __HIP_MEMORY_SCOPE_AGENT);
        if (wait) {
            while (__hip_atomic_load(&flags[bid * 16],
                                     __ATOMIC_RELAXED, __HIP_MEMORY_SCOPE_AGENT) < e)
                __builtin_amdgcn_s_sleep(1);
            __builtin_amdgcn_fence(__ATOMIC_ACQUIRE, "agent");   // inv L1+L2
        }
    }
    __syncthreads();
}

// ---------------------------------------------------------------------------
// M1: per-block redundant reduce of gemm partials + ppart + bm0 -> v0
// (in LDS only), redundant BN0 stats, then the f-column GEMM of layer 1.
// Block = (f = bid&127, gh = bid>>7). All reads plain (post-acquire).
// ---------------------------------------------------------------------------
__device__ void mlp_slab(float* u, int bid, int t,
    const float* __restrict__ part, const float* __restrict__ ppart,
    const float* __restrict__ bm0,
    const float* __restrict__ gbn, const float* __restrict__ bbn,
    const float* __restrict__ W, const float* __restrict__ bias,
    float* __restrict__ vout)
{
    float* h_s  = u;            // 64*129 = 8256
    float* sp1  = u + 8256;     // 1024
    float* sp2  = u + 9280;     // 1024
    float* sc   = u + 10304;    // 128
    float* sh   = u + 10432;    // 128
    float* wcol = u + 10560;    // 128
    float* pc   = u + 10688;    // 256
    const int f = bid & 127, gh = bid >> 7;
    if (t < 128) wcol[t] = W[t * 128 + f];
    const int f4 = (t & 31) * 4, tg = t >> 5;
    const float4 b4 = *(const float4*)(bm0 + f4);
    const bool own = (tg >> 2) == gh;
    float s1a[4] = {0.f, 0.f, 0.f, 0.f}, s2a[4] = {0.f, 0.f, 0.f, 0.f};
    #pragma unroll 4
    for (int i = 0; i < 16; i++) {
        const int g = tg * 16 + i;
        float4 v = *(const float4*)(ppart + g * 128 + f4);
        v.x += b4.x; v.y += b4.y; v.z += b4.z; v.w += b4.w;
        #pragma unroll
        for (int kc = 0; kc < 4; kc++) {
            float4 p = *(const float4*)(part + kc * 16384 + g * 128 + f4);
            v.x += p.x; v.y += p.y; v.z += p.z; v.w += p.w;
        }
        v.x = fmaxf(v.x, 0.f); v.y = fmaxf(v.y, 0.f);
        v.z = fmaxf(v.z, 0.f); v.w = fmaxf(v.w, 0.f);
        s1a[0] += v.x; s1a[1] += v.y; s1a[2] += v.z; s1a[3] += v.w;
        s2a[0] += v.x * v.x; s2a[1] += v.y * v.y;
        s2a[2] += v.z * v.z; s2a[3] += v.w * v.w;
        if (own) {
            const int r = g & 63;
            h_s[r * 129 + f4 + 0] = v.x; h_s[r * 129 + f4 + 1] = v.y;
            h_s[r * 129 + f4 + 2] = v.z; h_s[r * 129 + f4 + 3] = v.w;
        }
    }
    #pragma unroll
    for (int j = 0; j < 4; j++) {
        sp1[tg * 128 + f4 + j] = s1a[j];
        sp2[tg * 128 + f4 + j] = s2a[j];
    }
    __syncthreads();
    if (t < 128) {
        float S1 = 0.f, S2 = 0.f;
        #pragma unroll
        for (int q = 0; q < 8; q++) { S1 += sp1[q * 128 + t]; S2 += sp2[q * 128 + t]; }
        float m = S1 * (1.f / 128.f);
        float var = S2 * (1.f / 128.f) - m * m;
        float s = gbn[t] * rsqrtf(var + BN_EPS);
        sc[t] = s; sh[t] = bbn[t] - m * s;
    }
    __syncthreads();
    #pragma unroll
    for (int e = t; e < 8192; e += 256) {
        int g = e >> 7, k = e & 127;
        h_s[g * 129 + k] = h_s[g * 129 + k] * sc[k] + sh[k];
    }
    __syncthreads();
    {
        const int gl = t & 63, kh = t >> 6;
        float acc = 0.f;
        #pragma unroll 8
        for (int k = kh * 32; k < kh * 32 + 32; ++k)
            acc += h_s[gl * 129 + k] * wcol[k];
        pc[gl * 4 + kh] = acc;
    }
    __syncthreads();
    if (t < 64) {
        float v = fmaxf(pc[t * 4] + pc[t * 4 + 1] + pc[t * 4 + 2] + pc[t * 4 + 3]
                        + bias[f], 0.f);
        stg(&vout[(size_t)(gh * 64 + t) * 128 + f], v);
    }
}

// M2: same but vin is a dense post-relu [128x128] table.
__device__ void mlp_v(float* u, int bid, int t,
    const float* __restrict__ vin,
    const float* __restrict__ gbn, const float* __restrict__ bbn,
    const float* __restrict__ W, const float* __restrict__ bias,
    float* __restrict__ vout)
{
    float* h_s  = u;
    float* sp1  = u + 8256;
    float* sp2  = u + 9280;
    float* sc   = u + 10304;
    float* sh   = u + 10432;
    float* wcol = u + 10560;
    float* pc   = u + 10688;
    const int f = bid & 127, gh = bid >> 7;
    if (t < 128) wcol[t] = W[t * 128 + f];
    const int f4 = (t & 31) * 4, tg = t >> 5;
    const bool own = (tg >> 2) == gh;
    float s1a[4] = {0.f, 0.f, 0.f, 0.f}, s2a[4] = {0.f, 0.f, 0.f, 0.f};
    #pragma unroll 4
    for (int i = 0; i < 16; i++) {
        const int g = tg * 16 + i;
        float4 v = *(const float4*)(vin + (size_t)g * 128 + f4);
        s1a[0] += v.x; s1a[1] += v.y; s1a[2] += v.z; s1a[3] += v.w;
        s2a[0] += v.x * v.x; s2a[1] += v.y * v.y;
        s2a[2] += v.z * v.z; s2a[3] += v.w * v.w;
        if (own) {
            const int r = g & 63;
            h_s[r * 129 + f4 + 0] = v.x; h_s[r * 129 + f4 + 1] = v.y;
            h_s[r * 129 + f4 + 2] = v.z; h_s[r * 129 + f4 + 3] = v.w;
        }
    }
    #pragma unroll
    for (int j = 0; j < 4; j++) {
        sp1[tg * 128 + f4 + j] = s1a[j];
        sp2[tg * 128 + f4 + j] = s2a[j];
    }
    __syncthreads();
    if (t < 128) {
        float S1 = 0.f, S2 = 0.f;
        #pragma unroll
        for (int q = 0; q < 8; q++) { S1 += sp1[q * 128 + t]; S2 += sp2[q * 128 + t]; }
        float m = S1 * (1.f / 128.f);
        float var = S2 * (1.f / 128.f) - m * m;
        float s = gbn[t] * rsqrtf(var + BN_EPS);
        sc[t] = s; sh[t] = bbn[t] - m * s;
    }
    __syncthreads();
    #pragma unroll
    for (int e = t; e < 8192; e += 256) {
        int g = e >> 7, k = e & 127;
        h_s[g * 129 + k] = h_s[g * 129 + k] * sc[k] + sh[k];
    }
    __syncthreads();
    {
        const int gl = t & 63, kh = t >> 6;
        float acc = 0.f;
        #pragma unroll 8
        for (int k = kh * 32; k < kh * 32 + 32; ++k)
            acc += h_s[gl * 129 + k] * wcol[k];
        pc[gl * 4 + kh] = acc;
    }
    __syncthreads();
    if (t < 64) {
        float v = fmaxf(pc[t * 4] + pc[t * 4 + 1] + pc[t * 4 + 2] + pc[t * 4 + 3]
                        + bias[f], 0.f);
        stg(&vout[(size_t)(gh * 64 + t) * 128 + f], v);
    }
}

// ---------------------------------------------------------------------------
// Fused: F (conv 128 blks | gemm 64 blks 32x32xK1280 dbuf | 64 idle)
// |bar| M1(slab-reduce+stats+gemm) |bar| M2 |bar(exit>=128)| O.
// ---------------------------------------------------------------------------
__global__ __launch_bounds__(256) void k_fused(
    const float* __restrict__ x, const float* __restrict__ ew,
    const float* __restrict__ W1, const float* __restrict__ b1,
    const float* __restrict__ W2, const float* __restrict__ b2,
    const float* __restrict__ Wm0, const float* __restrict__ bm0,
    const float* __restrict__ gbn0, const float* __restrict__ bbn0,
    const float* __restrict__ Wm1, const float* __restrict__ bm1,
    const float* __restrict__ gbn1, const float* __restrict__ bbn1,
    const float* __restrict__ Wm2, const float* __restrict__ bm2,
    const float* __restrict__ gbn2, const float* __restrict__ bbn2,
    const float* __restrict__ Wo, const float* __restrict__ bo,
    float* __restrict__ ws, float* __restrict__ out)
{
    __shared__ __align__(16) float u[16128];   // 63KB union, reused per phase
    unsigned* bu = (unsigned*)ws;              // ctrl: 5120 u32 (20KB), memset 0
    float* part  = ws + 5120;                  // 4*16384 = 65536 (k-slices)
    float* ppart = part + 65536;               // 16384
    float* v1 = ppart + 16384;                 // 16384
    float* v2 = v1 + 16384;                    // 16384
    const int bid = blockIdx.x, t = threadIdx.x;

    // ======================= phase F =======================
    if (bid < 128) {
        // ---------------- conv path (one block per graph, r5-proven) --------
        float* ew_s     = u;             // [i][j] 4096 (raw)
        float* x_s      = u + 4096;      // x^T [k][i] 1024
        float* W1_s     = u + 5120;      // [k][f] 2048
        float* P_s      = u + 7168;      // [i][f] 8192 (dinv_i * P)
        float* b1_s     = u + 15360;     // 128
        float* dinv_s   = u + 15488;     // 64
        float* t_s      = u + 15552;     // 64
        float* zp       = u + 4096;      // overlay (x_s/W1_s dead): 16*132
        float* z_full   = u + 15616;     // 128
        float* pooled_s = u + 15744;     // 128
        float* pp2      = u + 15872;     // 256
        const int g = bid;
        {
            const float4* ew4 = (const float4*)(ew + g * EPG);
            float4* ews4 = (float4*)ew_s;
            #pragma unroll
            for (int i = 0; i < 4; i++) ews4[t + 256 * i] = ew4[t + 256 * i];
            const int xi = t & 63, k4 = (t >> 6) * 4;
            float4 xv = *(const float4*)(x + g * NPG * IN + xi * IN + k4);
            x_s[(k4 + 0) * 64 + xi] = xv.x;
            x_s[(k4 + 1) * 64 + xi] = xv.y;
            x_s[(k4 + 2) * 64 + xi] = xv.z;
            x_s[(k4 + 3) * 64 + xi] = xv.w;
            ((float4*)W1_s)[t]       = ((const float4*)W1)[t];
            ((float4*)W1_s)[t + 256] = ((const float4*)W1)[t + 256];
            if (t < 128) b1_s[t] = b1[t];
        }
        __syncthreads();

        if (t < NPG) {
            float s = 0.f;
            #pragma unroll 8
            for (int i = 0; i < NPG; i++) s += ew_s[i * NPG + t];
            dinv_s[t] = (s > 0.f) ? rsqrtf(s) : 0.f;
        }
        __syncthreads();

        {   // t_s[i] = dinv_i * (sum_j ew[i,j] dinv_j) / 64
            const int j = t & 63, q = t >> 6;
            const float dj = dinv_s[j];
            for (int i = q * 16; i < q * 16 + 16; i++) {
                float vv = ew_s[i * NPG + j] * dj;
                #pragma unroll
                for (int off = 32; off > 0; off >>= 1) vv += __shfl_down(vv, off, 64);
                if (j == 0) t_s[i] = dinv_s[i] * vv * (1.f / 64.f);
            }
        }

        {   // P' = dinv_i * (x @ W1)
            const int it = t & 15, ft = t >> 4;
            const int i0 = it * 4, f0 = ft * 8;
            float accp[4][8];
            #pragma unroll
            for (int a = 0; a < 4; a++)
                #pragma unroll
                for (int c = 0; c < 8; c++) accp[a][c] = 0.f;
            #pragma unroll
            for (int k = 0; k < IN; k++) {
                const float4 a4  = *(const float4*)(x_s + k * 64 + i0);
                const float4 b0v = *(const float4*)(W1_s + k * DM + f0);
                const float4 b1v = *(const float4*)(W1_s + k * DM + f0 + 4);
                const float av[4] = {a4.x, a4.y, a4.z, a4.w};
                const float bv[8] = {b0v.x, b0v.y, b0v.z, b0v.w, b1v.x, b1v.y, b1v.z, b1v.w};
                #pragma unroll
                for (int a = 0; a < 4; a++)
                    #pragma unroll
                    for (int c = 0; c < 8; c++) accp[a][c] += av[a] * bv[c];
            }
            #pragma unroll
            for (int a = 0; a < 4; a++) {
                const float di = dinv_s[i0 + a];
                float4* o = (float4*)(P_s + (i0 + a) * DM + f0);
                o[0] = make_float4(di * accp[a][0], di * accp[a][1],
                                   di * accp[a][2], di * accp[a][3]);
                o[1] = make_float4(di * accp[a][4], di * accp[a][5],
                                   di * accp[a][6], di * accp[a][7]);
            }
        }
        __syncthreads();

        {   // aggregation + z-partials
            const int jt = t & 15, ft = t >> 4;
            const int j0 = jt * 4, f0 = ft * 8;
            float acc[4][8];
            #pragma unroll
            for (int a = 0; a < 4; a++)
                #pragma unroll
                for (int c = 0; c < 8; c++) acc[a][c] = 0.f;
            #pragma unroll 4
            for (int k = 0; k < 64; k++) {
                const float4 a4  = *(const float4*)(ew_s + k * 64 + j0);
                const float4 b0v = *(const float4*)(P_s + k * DM + f0);
                const float4 b1v = *(const float4*)(P_s + k * DM + f0 + 4);
                const float av[4] = {a4.x, a4.y, a4.z, a4.w};
                const float bv[8] = {b0v.x, b0v.y, b0v.z, b0v.w, b1v.x, b1v.y, b1v.z, b1v.w};
                #pragma unroll
                for (int a = 0; a < 4; a++)
                    #pragma unroll
                    for (int c = 0; c < 8; c++) acc[a][c] += av[a] * bv[c];
            }
            float zpart[8];
            #pragma unroll
            for (int c = 0; c < 8; c++) zpart[c] = 0.f;
            #pragma unroll
            for (int a = 0; a < 4; a++) {
                const float dj = dinv_s[j0 + a], tj = t_s[j0 + a];
                #pragma unroll
                for (int c = 0; c < 8; c++) {
                    float h = fmaxf(dj * acc[a][c] + b1_s[f0 + c], 0.f);
                    zpart[c] += tj * h;
                }
            }
            float4* zo = (float4*)(zp + jt * 132 + f0);
            zo[0] = make_float4(zpart[0], zpart[1], zpart[2], zpart[3]);
            zo[1] = make_float4(zpart[4], zpart[5], zpart[6], zpart[7]);
        }
        __syncthreads();

        if (t < 128) {
            float s = 0.f;
            #pragma unroll
            for (int jt = 0; jt < 16; jt++) s += zp[jt * 132 + t];
            z_full[t] = s;
        }
        __syncthreads();

        {   // pooled = relu(z @ W2 + b2)
            const int c = t & 127, kh = t >> 7;
            float acc = 0.f;
            #pragma unroll 8
            for (int k = kh * 64; k < kh * 64 + 64; k++)
                acc += z_full[k] * W2[k * DM + c];
            pp2[kh * 128 + c] = acc;
        }
        __syncthreads();
        if (t < 128) pooled_s[t] = fmaxf(pp2[t] + pp2[128 + t] + b2[t], 0.f);
        __syncthreads();

        {   // ppart = pooled @ Wm0[0:128,:]
            const int f = t & 127, kh = t >> 7;
            float acc = 0.f;
            #pragma unroll 8
            for (int k = kh * 64; k < kh * 64 + 64; k++)
                acc += pooled_s[k] * Wm0[k * DM + f];
            pp2[kh * 128 + f] = acc;
        }
        __syncthreads();
        if (t < 128) stg(&ppart[g * DM + t], pp2[t] + pp2[128 + t]);
    } else if (bid < 192) {
        // ------ gemm: 64 blocks, (32g x 32f) tile, K=1280, dbuf chunk=64 -----
        const int c = bid - 128;
        const int gt = c & 3, fq = (c >> 2) & 3, kc = c >> 4;
        const int g0 = gt * 32, f0 = fq * 32, K0 = kc * 1280;
        float* a_s = u;              // 2 x 64 x 38 = 4864  (layout [k][g]+pad)
        float* b_s = u + 4864;       // 2 x 64 x 38 = 4864  (layout [k][f]+pad)
        const int gq = t & 15, ft = t >> 4;
        float a00 = 0.f, a01 = 0.f, a10 = 0.f, a11 = 0.f;
        float4 ra[2], rb[2];

        auto LOAD = [&](int ci) {
            #pragma unroll
            for (int it = 0; it < 2; it++) {
                int idx = it * 256 + t;
                int gg = idx >> 4, k4 = (idx & 15) * 4;
                int K = K0 + ci * 64 + k4;
                const float* src = (K < 1024) ? (x + (size_t)(g0 + gg) * 1024 + K)
                                              : (ew + (size_t)(g0 + gg) * 4096 + (K - 1024));
                ra[it] = *(const float4*)src;
                int kB = idx >> 3, fB = (idx & 7) * 4;
                rb[it] = *(const float4*)(Wm0 + (size_t)(128 + K0 + ci * 64 + kB) * 128
                                          + f0 + fB);
            }
        };
        auto STORE = [&](int buf) {
            float* ab = a_s + buf * 2432;
            float* bb = b_s + buf * 2432;
            #pragma unroll
            for (int it = 0; it < 2; it++) {
                int idx = it * 256 + t;
                int gg = idx >> 4, k4 = (idx & 15) * 4;
                ab[(k4 + 0) * 38 + gg] = fmaxf(ra[it].x, 0.f);
                ab[(k4 + 1) * 38 + gg] = fmaxf(ra[it].y, 0.f);
                ab[(k4 + 2) * 38 + gg] = fmaxf(ra[it].z, 0.f);
                ab[(k4 + 3) * 38 + gg] = fmaxf(ra[it].w, 0.f);
                int kB = idx >> 3, fB = (idx & 7) * 4;
                bb[kB * 38 + fB + 0] = rb[it].x;
                bb[kB * 38 + fB + 1] = rb[it].y;
                bb[kB * 38 + fB + 2] = rb[it].z;
                bb[kB * 38 + fB + 3] = rb[it].w;
            }
        };
        auto COMP = [&](int buf) {
            const float* ab = a_s + buf * 2432 + gq * 2;
            const float* bb = b_s + buf * 2432 + ft * 2;
            #pragma unroll 8
            for (int k = 0; k < 64; k++) {
                float x0 = ab[k * 38], x1 = ab[k * 38 + 1];
                float y0 = bb[k * 38], y1 = bb[k * 38 + 1];
                a00 += x0 * y0; a01 += x0 * y1;
                a10 += x1 * y0; a11 += x1 * y1;
            }
        };

        LOAD(0); STORE(0);
        __syncthreads();
        for (int ci = 0; ci < 20; ci++) {
            if (ci < 19) LOAD(ci + 1);          // global->reg, hides under COMP
            COMP(ci & 1);
            if (ci < 19) STORE((ci + 1) & 1);   // other buffer: no race
            __syncthreads();
        }
        const int gb = g0 + gq * 2, fb = f0 + ft * 2;
        stg(&part[kc * 16384 + (gb + 0) * 128 + fb + 0], a00);
        stg(&part[kc * 16384 + (gb + 0) * 128 + fb + 1], a01);
        stg(&part[kc * 16384 + (gb + 1) * 128 + fb + 0], a10);
        stg(&part[kc * 16384 + (gb + 1) * 128 + fb + 1], a11);
    }
    // blocks 192..255 idle in F, arrive immediately
    gbar(bu, 1u, bid, t, true);

    // ===================== M1 (slab-reduce + bn0), M2 =====================
    mlp_slab(u, bid, t, part, ppart, bm0, gbn0, bbn0, Wm1, bm1, v1);
    gbar(bu, 2u, bid, t, true);
    mlp_v(u, bid, t, v1, gbn1, bbn1, Wm2, bm2, v2);
    gbar(bu, 3u, bid, t, bid < 128);   // blocks >=128 arrive and exit
    if (bid >= 128) return;

    // ========= phase O: redundant BN2 stats + output (1 graph/blk) =========
    {
        float* Wo_s = u;            // 8192 (32KB)
        float* sp1  = u + 8192;     // 1024
        float* sp2  = u + 9216;     // 1024
        float* sc   = u + 10240;    // 128
        float* sh   = u + 10368;    // 128
        float* vrow = u + 10496;    // 128
        float* pc   = u + 10624;    // 256
        const int g = bid;
        {   // stage Wo 128x64 (2048 float4)
            const float4* wo4 = (const float4*)Wo;
            float4* wos4 = (float4*)Wo_s;
            #pragma unroll
            for (int it = 0; it < 8; it++) wos4[it * 256 + t] = wo4[it * 256 + t];
        }
        const int f4 = (t & 31) * 4, tg = t >> 5;
        float s1a[4] = {0.f, 0.f, 0.f, 0.f}, s2a[4] = {0.f, 0.f, 0.f, 0.f};
        #pragma unroll 4
        for (int i = 0; i < 16; i++) {
            const int g2 = tg * 16 + i;
            float4 v = *(const float4*)(v2 + (size_t)g2 * 128 + f4);
            s1a[0] += v.x; s1a[1] += v.y; s1a[2] += v.z; s1a[3] += v.w;
            s2a[0] += v.x * v.x; s2a[1] += v.y * v.y;
            s2a[2] += v.z * v.z; s2a[3] += v.w * v.w;
        }
        #pragma unroll
        for (int j = 0; j < 4; j++) {
            sp1[tg * 128 + f4 + j] = s1a[j];
            sp2[tg * 128 + f4 + j] = s2a[j];
        }
        __syncthreads();
        if (t < 128) {
            float S1 = 0.f, S2 = 0.f;
            #pragma unroll
            for (int q = 0; q < 8; q++) { S1 += sp1[q * 128 + t]; S2 += sp2[q * 128 + t]; }
            float m = S1 * (1.f / 128.f);
            float var = S2 * (1.f / 128.f) - m * m;
            float s = gbn2[t] * rsqrtf(var + BN_EPS);
            sc[t] = s; sh[t] = bbn2[t] - m * s;
        }
        __syncthreads();
        if (t < 128) vrow[t] = v2[(size_t)g * 128 + t] * sc[t] + sh[t];
        __syncthreads();
        {   // 64 o-cols x 4 k-quarters
            const int o = t & 63, kh = t >> 6;
            float acc = 0.f;
            #pragma unroll 8
            for (int k = kh * 32; k < kh * 32 + 32; k++)
                acc += vrow[k] * Wo_s[k * 64 + o];
            pc[kh * 64 + o] = acc;
        }
        __syncthreads();
        if (t < 64)
            out[g * NOUT + t] = pc[t] + pc[64 + t] + pc[128 + t] + pc[192 + t] + bo[t];
    }
}

extern "C" void kernel_launch(void* const* d_in, const int* in_sizes, int n_in,
                              void* d_out, int out_size, void* d_ws, size_t ws_size,
                              hipStream_t stream)
{
    const float* x   = (const float*)d_in[0];
    const float* ew  = (const float*)d_in[2];
    const float* W1  = (const float*)d_in[4];
    const float* b1  = (const float*)d_in[5];
    const float* W2  = (const float*)d_in[6];
    const float* b2  = (const float*)d_in[7];
    const float* Wm0 = (const float*)d_in[8];
    const float* bm0 = (const float*)d_in[9];
    const float* g0  = (const float*)d_in[10];
    const float* be0 = (const float*)d_in[11];
    const float* Wm1 = (const float*)d_in[12];
    const float* bm1 = (const float*)d_in[13];
    const float* g1  = (const float*)d_in[14];
    const float* be1 = (const float*)d_in[15];
    const float* Wm2 = (const float*)d_in[16];
    const float* bm2 = (const float*)d_in[17];
    const float* g2  = (const float*)d_in[18];
    const float* be2 = (const float*)d_in[19];
    const float* Wo  = (const float*)d_in[20];
    const float* bo  = (const float*)d_in[21];

    float* ws = (float*)d_ws;
    // zero barrier ctrl only (20 KB)
    hipMemsetAsync(d_ws, 0, 20480, stream);
    k_fused<<<256, 256, 0, stream>>>(x, ew, W1, b1, W2, b2,
                                     Wm0, bm0, g0, be0,
                                     Wm1, bm1, g1, be1,
                                     Wm2, bm2, g2, be2,
                                     Wo, bo, ws, (float*)d_out);
}

// Round 7
// 132.519 us; speedup vs baseline: 1.1659x; 1.1659x over previous
//
#include <hip/hip_runtime.h>

#define NG 128      // graphs
#define NPG 64      // nodes per graph
#define IN 16
#define DM 128      // d_model
#define NOUT 64
#define EPG 4096    // edges per graph (64x64)
#define NCH 128     // gemm chunks: 64 k-chunks(80) x 2 f-halves(64)
#define BN_EPS 1e-5f

// ---------------------------------------------------------------------------
// K_A "front": 256 blocks x 512 threads (8 waves = 2/SIMD for latency hiding;
// r0's 256-thread version was 1 wave/SIMD and latency-bound, ~20us).
//   blocks 0..127  = conv1 per graph -> pooled -> ppart (Wm0[0:128] product)
//   blocks 128..255 = big-GEMM x/ew chunks (80k x 64f) -> part
// Cross-kernel coherence via kernel boundaries (r0-proven; no fences).
// ---------------------------------------------------------------------------
__global__ __launch_bounds__(512) void k_front(
    const float* __restrict__ x, const float* __restrict__ ew,
    const float* __restrict__ W1, const float* __restrict__ b1,
    const float* __restrict__ W2, const float* __restrict__ b2,
    const float* __restrict__ Wm0,
    float* __restrict__ part, float* __restrict__ ppart,
    float* __restrict__ stats)
{
    __shared__ __align__(16) float u[16128];   // 63KB union
    const int bid = blockIdx.x, t = threadIdx.x;

    if (bid < 128) {
        // ---------------- conv path (one block per graph) ----------------
        float* ew_s     = u;             // [i][j] 4096 (raw, never rescaled)
        float* x_s      = u + 4096;      // x^T [k][i] 1024
        float* W1_s     = u + 5120;      // [k][f] 2048
        float* P_s      = u + 7168;      // [i][f] 8192 (holds dinv_i * P)
        float* b1_s     = u + 15360;     // 128
        float* dinv_s   = u + 15488;     // 64
        float* t_s      = u + 15552;     // 64
        float* zp       = u + 4096;      // overlay (x_s/W1_s dead after P): 16*132
        float* z_full   = u + 15616;     // 128
        float* pooled_s = u + 15744;     // 128
        float* pp4      = u + 4096;      // overlay 2 (zp dead after z): 512
        const int g = bid;
        if (bid == 0) {
            for (int i = t; i < 768; i += 512) stats[i] = 0.f;
        }
        // stage: ew (vectorized), x transposed (t<256), W1 direct, b1
        {
            const float4* ew4 = (const float4*)(ew + g * EPG);
            float4* ews4 = (float4*)ew_s;
            ews4[t]       = ew4[t];
            ews4[t + 512] = ew4[t + 512];
            if (t < 256) {
                const int xi = t & 63, k4 = (t >> 6) * 4;
                float4 xv = *(const float4*)(x + g * NPG * IN + xi * IN + k4);
                x_s[(k4 + 0) * 64 + xi] = xv.x;
                x_s[(k4 + 1) * 64 + xi] = xv.y;
                x_s[(k4 + 2) * 64 + xi] = xv.z;
                x_s[(k4 + 3) * 64 + xi] = xv.w;
            }
            ((float4*)W1_s)[t] = ((const float4*)W1)[t];   // 512 f4 = 2048
            if (t < 128) b1_s[t] = b1[t];
        }
        __syncthreads();

        // dinv: column sums of raw ew
        if (t < NPG) {
            float s = 0.f;
            #pragma unroll 8
            for (int i = 0; i < NPG; i++) s += ew_s[i * NPG + t];
            dinv_s[t] = (s > 0.f) ? rsqrtf(s) : 0.f;
        }
        __syncthreads();

        // t_s[i] = dinv_i * (sum_j ew[i,j] dinv_j) / 64  (8 waves x 8 rows)
        {
            const int j = t & 63, q = t >> 6;     // q = wave 0..7
            const float dj = dinv_s[j];
            for (int i = q * 8; i < q * 8 + 8; i++) {
                float vv = ew_s[i * NPG + j] * dj;
                #pragma unroll
                for (int off = 32; off > 0; off >>= 1) vv += __shfl_down(vv, off, 64);
                if (j == 0) t_s[i] = dinv_s[i] * vv * (1.f / 64.f);
            }
        }

        // P' = dinv_i * (x @ W1) (64x128x16), 16x32 thread grid, 4x4 acc
        // (no barrier needed between t_s and P: disjoint LDS regions)
        {
            const int it = t & 15, ft = t >> 4;   // ft 0..31
            const int i0 = it * 4, f0 = ft * 4;
            float accp[4][4];
            #pragma unroll
            for (int a = 0; a < 4; a++)
                #pragma unroll
                for (int c = 0; c < 4; c++) accp[a][c] = 0.f;
            #pragma unroll
            for (int k = 0; k < IN; k++) {
                const float4 a4 = *(const float4*)(x_s + k * 64 + i0);
                const float4 b4 = *(const float4*)(W1_s + k * DM + f0);
                const float av[4] = {a4.x, a4.y, a4.z, a4.w};
                const float bv[4] = {b4.x, b4.y, b4.z, b4.w};
                #pragma unroll
                for (int a = 0; a < 4; a++)
                    #pragma unroll
                    for (int c = 0; c < 4; c++) accp[a][c] += av[a] * bv[c];
            }
            #pragma unroll
            for (int a = 0; a < 4; a++) {
                const float di = dinv_s[i0 + a];
                *(float4*)(P_s + (i0 + a) * DM + f0) =
                    make_float4(di * accp[a][0], di * accp[a][1],
                                di * accp[a][2], di * accp[a][3]);
            }
        }
        __syncthreads();

        // aggregation: h[j,f] = relu(dinv_j * sum_k ew[k,j] P'[k,f] + b1[f]);
        // z-partials per thread -> zp. 16x32 grid, 4x4 acc.
        {
            const int jt = t & 15, ft = t >> 4;
            const int j0 = jt * 4, f0 = ft * 4;
            float acc[4][4];
            #pragma unroll
            for (int a = 0; a < 4; a++)
                #pragma unroll
                for (int c = 0; c < 4; c++) acc[a][c] = 0.f;
            #pragma unroll 4
            for (int k = 0; k < 64; k++) {
                const float4 a4 = *(const float4*)(ew_s + k * 64 + j0);
                const float4 b4 = *(const float4*)(P_s + k * DM + f0);
                const float av[4] = {a4.x, a4.y, a4.z, a4.w};
                const float bv[4] = {b4.x, b4.y, b4.z, b4.w};
                #pragma unroll
                for (int a = 0; a < 4; a++)
                    #pragma unroll
                    for (int c = 0; c < 4; c++) acc[a][c] += av[a] * bv[c];
            }
            float zpart[4];
            #pragma unroll
            for (int c = 0; c < 4; c++) zpart[c] = 0.f;
            #pragma unroll
            for (int a = 0; a < 4; a++) {
                const float dj = dinv_s[j0 + a], tj = t_s[j0 + a];
                #pragma unroll
                for (int c = 0; c < 4; c++) {
                    float h = fmaxf(dj * acc[a][c] + b1_s[f0 + c], 0.f);
                    zpart[c] += tj * h;
                }
            }
            *(float4*)(zp + jt * 132 + f0) =
                make_float4(zpart[0], zpart[1], zpart[2], zpart[3]);
        }
        __syncthreads();

        // z (LDS-resident only)
        if (t < 128) {
            float s = 0.f;
            #pragma unroll
            for (int jt = 0; jt < 16; jt++) s += zp[jt * 132 + t];
            z_full[t] = s;
        }
        __syncthreads();

        // pooled = relu(z @ W2 + b2): thread (c = t&127, kh = t>>7 in 0..3)
        {
            const int c = t & 127, kh = t >> 7;
            float acc = 0.f;
            #pragma unroll 8
            for (int k = kh * 32; k < kh * 32 + 32; k++)
                acc += z_full[k] * W2[k * DM + c];
            pp4[kh * 128 + c] = acc;    // overlay: zp dead now
        }
        __syncthreads();
        if (t < 128)
            pooled_s[t] = fmaxf(pp4[t] + pp4[128 + t] + pp4[256 + t] + pp4[384 + t]
                                + b2[t], 0.f);
        __syncthreads();

        // ppart = pooled @ Wm0[0:128,:]
        {
            const int f = t & 127, kh = t >> 7;
            float acc = 0.f;
            #pragma unroll 8
            for (int k = kh * 32; k < kh * 32 + 32; k++)
                acc += pooled_s[k] * Wm0[k * DM + f];
            pp4[kh * 128 + f] = acc;
        }
        __syncthreads();
        if (t < 128)
            ppart[g * DM + t] = pp4[t] + pp4[128 + t] + pp4[256 + t] + pp4[384 + t];
    } else {
        // ---------------- gemm x/ew chunk path (K=80) ----------------
        const int c = bid - 128;
        const int kc = c >> 1, fh = c & 1;
        const int K0 = kc * 80;          // feat col base in x|ew space (0..5120)
        float* a_s = u;                  // [k][g] 80*132 = 10560
        float* b_s = u + 10560;          // [k][fl] 80*64 = 5120

        // reg-batched float4 staging (all loads in flight before LDS writes)
        float4 ra[4], ra2, rb[3];
        #pragma unroll
        for (int it = 0; it < 4; it++) {             // k 0..63: 2048 f4
            int idx = it * 512 + t;
            int gg = idx >> 4, k4 = (idx & 15) << 2;
            int K = K0 + k4;
            const float* src = (K < 1024) ? (x + gg * 1024 + K)
                                          : (ew + gg * 4096 + (K - 1024));
            ra[it] = *(const float4*)src;
        }
        {                                            // k 64..79: 512 f4
            int gg = t >> 2, k4 = 64 + ((t & 3) << 2);
            int K = K0 + k4;
            const float* src = (K < 1024) ? (x + gg * 1024 + K)
                                          : (ew + gg * 4096 + (K - 1024));
            ra2 = *(const float4*)src;
        }
        #pragma unroll
        for (int it = 0; it < 3; it++) {             // Wm0 slice: 1280 f4
            int idx = it * 512 + t;
            if (idx < 1280) {
                int k = idx >> 4, fl4 = (idx & 15) << 2;
                rb[it] = *(const float4*)(Wm0 + (size_t)(128 + K0 + k) * 128
                                          + fh * 64 + fl4);
            }
        }
        #pragma unroll
        for (int it = 0; it < 4; it++) {
            int idx = it * 512 + t;
            int gg = idx >> 4, k4 = (idx & 15) << 2;
            a_s[(k4 + 0) * 132 + gg] = fmaxf(ra[it].x, 0.f);
            a_s[(k4 + 1) * 132 + gg] = fmaxf(ra[it].y, 0.f);
            a_s[(k4 + 2) * 132 + gg] = fmaxf(ra[it].z, 0.f);
            a_s[(k4 + 3) * 132 + gg] = fmaxf(ra[it].w, 0.f);
        }
        {
            int gg = t >> 2, k4 = 64 + ((t & 3) << 2);
            a_s[(k4 + 0) * 132 + gg] = fmaxf(ra2.x, 0.f);
            a_s[(k4 + 1) * 132 + gg] = fmaxf(ra2.y, 0.f);
            a_s[(k4 + 2) * 132 + gg] = fmaxf(ra2.z, 0.f);
            a_s[(k4 + 3) * 132 + gg] = fmaxf(ra2.w, 0.f);
        }
        #pragma unroll
        for (int it = 0; it < 3; it++) {
            int idx = it * 512 + t;
            if (idx < 1280) {
                int k = idx >> 4, fl4 = (idx & 15) << 2;
                *(float4*)(b_s + k * 64 + fl4) = rb[it];
            }
        }
        __syncthreads();

        const int gthr = t & 31, fthr = t >> 5;   // 32 x 16
        const int g0 = gthr * 4, f0 = fthr * 4;
        float acc[4][4];
        #pragma unroll
        for (int i = 0; i < 4; i++)
            #pragma unroll
            for (int jx = 0; jx < 4; jx++) acc[i][jx] = 0.f;

        #pragma unroll 4
        for (int k = 0; k < 80; k++) {
            const float4 a4 = *(const float4*)(a_s + k * 132 + g0);
            const float4 b4 = *(const float4*)(b_s + k * 64 + f0);
            const float av[4] = {a4.x, a4.y, a4.z, a4.w};
            const float bv[4] = {b4.x, b4.y, b4.z, b4.w};
            #pragma unroll
            for (int i = 0; i < 4; i++)
                #pragma unroll
                for (int jx = 0; jx < 4; jx++) acc[i][jx] += av[i] * bv[jx];
        }

        float* pp = part + (size_t)c * 8192;    // [g][fl] 128x64
        #pragma unroll
        for (int i = 0; i < 4; i++)
            *(float4*)(pp + (g0 + i) * 64 + f0) =
                make_float4(acc[i][0], acc[i][1], acc[i][2], acc[i][3]);
    }
}

// ---------------------------------------------------------------------------
// K_B: slim reduce (float4 loads): 128 chunk-partials + ppart + bm0 + relu
// -> v0; BN0 stats atomics. 256 blocks = 32 g-tiles x 8 f-grps. (r0 verbatim)
// ---------------------------------------------------------------------------
__global__ __launch_bounds__(256) void k_reduce_bn0(
    const float* __restrict__ part, const float* __restrict__ ppart,
    const float* __restrict__ bm0, float* __restrict__ v0,
    float* __restrict__ stats0)
{
    __shared__ float r1[1024];    // [ch][gl][16f]
    __shared__ float sv[64], sv2[64];
    const int bx = blockIdx.x, t = threadIdx.x;
    const int fgrp = bx & 7, gt = bx >> 3;
    const int f4 = t & 3, gl = (t >> 2) & 3, ch = t >> 4;
    const int g = gt * 4 + gl;
    const int fbase = fgrp * 16 + f4 * 4;
    const int fh = fbase >> 6, fl = fbase & 63;

    const float4* p = (const float4*)part
                    + ((size_t)(2 * (ch * 4) + fh) * 8192 + g * 64 + fl) / 4;
    float4 v = make_float4(0.f, 0.f, 0.f, 0.f);
    #pragma unroll
    for (int cc = 0; cc < 4; cc++) {
        float4 x4 = p[(size_t)cc * 4096];   // +2*8192 floats per k-chunk
        v.x += x4.x; v.y += x4.y; v.z += x4.z; v.w += x4.w;
    }
    float* r = r1 + ch * 64 + gl * 16 + f4 * 4;
    r[0] = v.x; r[1] = v.y; r[2] = v.z; r[3] = v.w;
    __syncthreads();

    if (t < 64) {
        const int fsub = t & 15, gl2 = t >> 4;
        const int f = fgrp * 16 + fsub, gg = gt * 4 + gl2;
        float s = bm0[f] + ppart[gg * DM + f];
        #pragma unroll
        for (int c2 = 0; c2 < 16; c2++) s += r1[c2 * 64 + gl2 * 16 + fsub];
        s = fmaxf(s, 0.f);
        v0[gg * DM + f] = s;
        sv[t] = s; sv2[t] = s * s;
    }
    __syncthreads();
    if (t < 16) {
        float s1 = sv[t] + sv[t + 16] + sv[t + 32] + sv[t + 48];
        float s2 = sv2[t] + sv2[t + 16] + sv2[t + 32] + sv2[t + 48];
        atomicAdd(&stats0[(fgrp * 16 + t) * 2], s1);
        atomicAdd(&stats0[(fgrp * 16 + t) * 2 + 1], s2);
    }
}

// ---------------------------------------------------------------------------
// K5/K6: one MLP layer. 256 blocks = 128 f-cols x 2 graph-halves. (r0 verbatim)
// ---------------------------------------------------------------------------
__global__ __launch_bounds__(256) void k_mlp(
    const float* __restrict__ vin, const float* __restrict__ statsin,
    const float* __restrict__ gbn, const float* __restrict__ bbn,
    const float* __restrict__ W, const float* __restrict__ bias,
    float* __restrict__ vout, float* __restrict__ statsout)
{
    __shared__ float scale_s[128], shift_s[128];
    __shared__ float wcol[128];
    __shared__ float pc[256];
    __shared__ float h_s[64 * 129];
    const int b = blockIdx.x, t = threadIdx.x;
    const int f = b & 127, gh = b >> 7;
    if (t < 128) {
        float s1 = statsin[t * 2], s2 = statsin[t * 2 + 1];
        float m = s1 * (1.f / 128.f);
        float var = s2 * (1.f / 128.f) - m * m;
        float sc = gbn[t] * rsqrtf(var + BN_EPS);
        scale_s[t] = sc;
        shift_s[t] = bbn[t] - m * sc;
        wcol[t] = W[t * 128 + f];
    }
    __syncthreads();
    const int g0r = gh * 64;
    const float4* vin4 = (const float4*)(vin + g0r * 128);
    #pragma unroll
    for (int it = 0; it < 8; ++it) {
        int idx = it * 256 + t;            // 2048 float4 = 64 rows x 128
        int gl = idx >> 5, k4 = (idx & 31) * 4;
        float4 vv = vin4[idx];
        float* hp = h_s + gl * 129 + k4;
        hp[0] = vv.x * scale_s[k4 + 0] + shift_s[k4 + 0];
        hp[1] = vv.y * scale_s[k4 + 1] + shift_s[k4 + 1];
        hp[2] = vv.z * scale_s[k4 + 2] + shift_s[k4 + 2];
        hp[3] = vv.w * scale_s[k4 + 3] + shift_s[k4 + 3];
    }
    __syncthreads();
    {
        const int gl = t & 63, kh = t >> 6;
        float acc = 0.f;
        #pragma unroll 8
        for (int k = kh * 32; k < kh * 32 + 32; ++k) acc += h_s[gl * 129 + k] * wcol[k];
        pc[gl * 4 + kh] = acc;
    }
    __syncthreads();
    if (t < 64) {   // wave 0
        float v = fmaxf(pc[t * 4] + pc[t * 4 + 1] + pc[t * 4 + 2] + pc[t * 4 + 3]
                        + bias[f], 0.f);
        vout[(size_t)(g0r + t) * 128 + f] = v;
        float s1 = v, s2 = v * v;
        #pragma unroll
        for (int off = 32; off > 0; off >>= 1) {
            s1 += __shfl_down(s1, off, 64);
            s2 += __shfl_down(s2, off, 64);
        }
        if (t == 0) {
            atomicAdd(&statsout[f * 2], s1);
            atomicAdd(&statsout[f * 2 + 1], s2);
        }
    }
}

// ---------------------------------------------------------------------------
// K7: output layer (BN2 folded at load). Block = 2 graph rows. (r0 verbatim)
// ---------------------------------------------------------------------------
__global__ __launch_bounds__(128) void k_out(
    const float* __restrict__ vin, const float* __restrict__ statsin,
    const float* __restrict__ gbn, const float* __restrict__ bbn,
    const float* __restrict__ Wo, const float* __restrict__ bo,
    float* __restrict__ out)
{
    __shared__ __align__(16) float Wo_s[128 * 64];   // 32KB
    __shared__ float vrow[2][128];
    __shared__ float scale_s[128], shift_s[128];
    const int b = blockIdx.x, t = threadIdx.x, g0 = b * 2;
    {
        float s1 = statsin[t * 2], s2 = statsin[t * 2 + 1];
        float m = s1 * (1.f / 128.f);
        float var = s2 * (1.f / 128.f) - m * m;
        float sc = gbn[t] * rsqrtf(var + BN_EPS);
        scale_s[t] = sc;
        shift_s[t] = bbn[t] - m * sc;
    }
    __syncthreads();
    {
        const float4* wo4 = (const float4*)Wo;
        float4* wos4 = (float4*)Wo_s;
        #pragma unroll
        for (int it = 0; it < 16; it++) wos4[it * 128 + t] = wo4[it * 128 + t];
    }
    if (t < 64) {
        int g2 = t >> 5, k4 = (t & 31) * 4;
        float4 vv = ((const float4*)(vin + g0 * 128))[t];
        vrow[g2][k4 + 0] = vv.x * scale_s[k4 + 0] + shift_s[k4 + 0];
        vrow[g2][k4 + 1] = vv.y * scale_s[k4 + 1] + shift_s[k4 + 1];
        vrow[g2][k4 + 2] = vv.z * scale_s[k4 + 2] + shift_s[k4 + 2];
        vrow[g2][k4 + 3] = vv.w * scale_s[k4 + 3] + shift_s[k4 + 3];
    }
    __syncthreads();
    const int g2 = t >> 6, o = t & 63;
    float acc = bo[o];
    #pragma unroll 8
    for (int k = 0; k < 128; k++) acc += vrow[g2][k] * Wo_s[k * 64 + o];
    out[(g0 + g2) * NOUT + o] = acc;
}

extern "C" void kernel_launch(void* const* d_in, const int* in_sizes, int n_in,
                              void* d_out, int out_size, void* d_ws, size_t ws_size,
                              hipStream_t stream)
{
    const float* x   = (const float*)d_in[0];
    const float* ew  = (const float*)d_in[2];
    const float* W1  = (const float*)d_in[4];
    const float* b1  = (const float*)d_in[5];
    const float* W2  = (const float*)d_in[6];
    const float* b2  = (const float*)d_in[7];
    const float* Wm0 = (const float*)d_in[8];
    const float* bm0 = (const float*)d_in[9];
    const float* g0  = (const float*)d_in[10];
    const float* be0 = (const float*)d_in[11];
    const float* Wm1 = (const float*)d_in[12];
    const float* bm1 = (const float*)d_in[13];
    const float* g1  = (const float*)d_in[14];
    const float* be1 = (const float*)d_in[15];
    const float* Wm2 = (const float*)d_in[16];
    const float* bm2 = (const float*)d_in[17];
    const float* g2  = (const float*)d_in[18];
    const float* be2 = (const float*)d_in[19];
    const float* Wo  = (const float*)d_in[20];
    const float* bo  = (const float*)d_in[21];

    float* ws     = (float*)d_ws;
    float* part   = ws;                       // 128*8192 = 1048576
    float* ppartb = part + NCH * 8192;        // 16384
    float* v0     = ppartb + 16384;           // 16384
    float* v1     = v0 + 16384;               // 16384
    float* v2     = v1 + 16384;               // 16384
    float* stats  = v2 + 16384;               // 768 (stats0|stats1|stats2)

    k_front<<<256, 512, 0, stream>>>(x, ew, W1, b1, W2, b2, Wm0, part, ppartb, stats);
    k_reduce_bn0<<<256, 256, 0, stream>>>(part, ppartb, bm0, v0, stats);
    k_mlp<<<256, 256, 0, stream>>>(v0, stats,       g0, be0, Wm1, bm1, v1, stats + 256);
    k_mlp<<<256, 256, 0, stream>>>(v1, stats + 256, g1, be1, Wm2, bm2, v2, stats + 512);
    k_out<<<NOUT, 128, 0, stream>>>(v2, stats + 512, g2, be2, Wo, bo, (float*)d_out);
}